// Round 4
// baseline (18608.340 us; speedup 1.0000x reference)
//
#include <hip/hip_runtime.h>
#include <hip/hip_bf16.h>
#include <stdint.h>

#define NN 150000
#define NE 150000
#define G 128
#define D 512
#define L 5
#define MAXD 20
#define EPS 1e-5f

typedef unsigned short u16;
typedef unsigned int u32;
typedef __attribute__((ext_vector_type(8))) short bf16x8;
typedef __attribute__((ext_vector_type(4))) float f32x4;

__device__ __forceinline__ float bf2f(u16 u) {
    union { u32 i; float f; } v; v.i = ((u32)u) << 16; return v.f;
}
__device__ __forceinline__ u16 f2bf(float f) {
    union { float f; u32 i; } v; v.f = f;
    u32 r = v.i + 0x7FFF + ((v.i >> 16) & 1);
    return (u16)(r >> 16);
}
// split fp32 -> (hi, lo) bf16 pair
__device__ __forceinline__ void split2(float v, u16& hi, u16& lo) {
    hi = f2bf(v);
    lo = f2bf(v - bf2f(hi));
}

// ---------------- zero fill ----------------
__global__ void k_zero(float* __restrict__ p, int n) {
    int i = blockIdx.x * 256 + threadIdx.x;
    if (i < n) p[i] = 0.0f;
}

// ---------------- degree ----------------
__global__ void k_deg_count(const int* __restrict__ row, int* __restrict__ degint) {
    int e = blockIdx.x * 256 + threadIdx.x;
    if (e < NE) atomicAdd(&degint[row[e]], 1);
}
__global__ void k_deg_fin(const int* __restrict__ degint, float* __restrict__ deg,
                          float* __restrict__ dis) {
    int n = blockIdx.x * 256 + threadIdx.x;
    if (n < NN) {
        float d = (float)degint[n] + 1.0f;
        deg[n] = d;
        dis[n] = rsqrtf(d);
    }
}

// ---------------- node encoder (fp32 in, hi/lo bf16 out) ----------------
__global__ void k_encoder(const int* __restrict__ x, const int* __restrict__ dep,
                          const float* __restrict__ te, const float* __restrict__ ae,
                          const float* __restrict__ de,
                          u16* __restrict__ hh, u16* __restrict__ hl) {
    int n = blockIdx.x, t = threadIdx.x;  // 256 threads, 2 cols each
    int t0 = x[2 * n], t1 = x[2 * n + 1];
    int dp = dep[n]; if (dp > MAXD) dp = MAXD;
    float2 a = ((const float2*)(te + (size_t)t0 * D))[t];
    float2 b = ((const float2*)(ae + (size_t)t1 * D))[t];
    float2 c = ((const float2*)(de + (size_t)dp * D))[t];
    float v0 = a.x + b.x + c.x;
    float v1 = a.y + b.y + c.y;
    u16 h0, l0, h1, l1;
    split2(v0, h0, l0); split2(v1, h1, l1);
    ((u32*)(hh + (size_t)n * D))[t] = (u32)h0 | ((u32)h1 << 16);
    ((u32*)(hl + (size_t)n * D))[t] = (u32)l0 | ((u32)l1 << 16);
}

// -------- transpose+split lin_w: Wh/Wl[l][n][k] = split(W[l][k][n]) --------
__global__ void k_wsplit(const float* __restrict__ W, u16* __restrict__ Wh,
                         u16* __restrict__ Wl) {
    __shared__ float tile[32][33];
    int l = blockIdx.z, kt = blockIdx.y, nt = blockIdx.x;
    const float* Wlp = W + (size_t)l * D * D;
    int tx = threadIdx.x, ty = threadIdx.y;  // 32 x 8
    #pragma unroll
    for (int i = 0; i < 32; i += 8)
        tile[ty + i][tx] = Wlp[(size_t)(kt * 32 + ty + i) * D + nt * 32 + tx];
    __syncthreads();
    #pragma unroll
    for (int i = 0; i < 32; i += 8) {
        float v = tile[tx][ty + i];
        u16 hi, lo; split2(v, hi, lo);
        size_t o = (size_t)l * D * D + (size_t)(nt * 32 + ty + i) * D + kt * 32 + tx;
        Wh[o] = hi; Wl[o] = lo;
    }
}

// ---------------- vn init ----------------
__global__ void k_vninit(const float* __restrict__ vw, float* __restrict__ vn) {
    int i = blockIdx.x * 256 + threadIdx.x;
    vn[i] = vw[i & (D - 1)];
}

// ---------------- vnW = vn @ W + lin_b (fp32, tiny) ----------------
__global__ void k_vnw(const float* __restrict__ vn, const float* __restrict__ W,
                      const float* __restrict__ lb, float* __restrict__ vnW) {
    int g = blockIdx.x, c = threadIdx.x;  // 512 threads
    __shared__ float sv[D];
    sv[c] = vn[g * D + c];
    __syncthreads();
    float acc = lb[c];
    for (int k = 0; k < D; k++) acc = fmaf(sv[k], W[(size_t)k * D + c], acc);
    vnW[g * D + c] = acc;
}

// ------- split-bf16 GEMM: hx = (hh+hl) @ (Wh+Wl)^T_layout + vnW[batch] -----
// 3 MFMA products per tile: Ah*Bh + Ah*Bl + Al*Bh (Al*Bl dropped, ~2^-18)
__global__ __launch_bounds__(256) void k_gemm3(
    const u16* __restrict__ Ahp, const u16* __restrict__ Alp,
    const u16* __restrict__ Bhp, const u16* __restrict__ Blp,
    const float* __restrict__ vnW, const int* __restrict__ batch,
    float* __restrict__ hx) {
    __shared__ __align__(16) u16 sAh[128 * 32];
    __shared__ __align__(16) u16 sAl[128 * 32];
    __shared__ __align__(16) u16 sBh[128 * 32];
    __shared__ __align__(16) u16 sBl[128 * 32];
    const int tid = threadIdx.x;
    const int wave = tid >> 6, ln = tid & 63;
    const long row0 = (long)blockIdx.x * 128;
    const int col0 = blockIdx.y * 128;

    f32x4 acc[4][4] = {};
    const int wm = wave & 1, wn = wave >> 1;
    const int lrow = ln & 15, lq = ln >> 4, lk = (ln >> 4) * 8;

    int s_row[2], s_col[2];
    #pragma unroll
    for (int i = 0; i < 2; i++) {
        int idx = tid + 256 * i;          // 512 chunks of 8 u16 = one 128x32 tile
        s_row[i] = idx >> 2;
        s_col[i] = (idx & 3) * 8;
    }

    for (int kt = 0; kt < D / 32; ++kt) {
        uint4 vah[2], val[2], vbh[2], vbl[2];
        #pragma unroll
        for (int i = 0; i < 2; i++) {
            long ar = row0 + s_row[i];
            if (ar >= NN) ar = NN - 1;    // clamp (stores guarded)
            size_t ao = (size_t)ar * D + kt * 32 + s_col[i];
            size_t bo = (size_t)(col0 + s_row[i]) * D + kt * 32 + s_col[i];
            vah[i] = *(const uint4*)(Ahp + ao);
            val[i] = *(const uint4*)(Alp + ao);
            vbh[i] = *(const uint4*)(Bhp + bo);
            vbl[i] = *(const uint4*)(Blp + bo);
        }
        __syncthreads();
        #pragma unroll
        for (int i = 0; i < 2; i++) {
            int o = s_row[i] * 32 + s_col[i];
            *(uint4*)&sAh[o] = vah[i];
            *(uint4*)&sAl[o] = val[i];
            *(uint4*)&sBh[o] = vbh[i];
            *(uint4*)&sBl[o] = vbl[i];
        }
        __syncthreads();
        bf16x8 ah[4], al[4], bh[4], bl[4];
        #pragma unroll
        for (int i = 0; i < 4; i++) {
            int ao = (wm * 64 + i * 16 + lrow) * 32 + lk;
            int bo = (wn * 64 + i * 16 + lrow) * 32 + lk;
            ah[i] = *(const bf16x8*)&sAh[ao];
            al[i] = *(const bf16x8*)&sAl[ao];
            bh[i] = *(const bf16x8*)&sBh[bo];
            bl[i] = *(const bf16x8*)&sBl[bo];
        }
        #pragma unroll
        for (int i = 0; i < 4; i++) {
            #pragma unroll
            for (int j = 0; j < 4; j++) {
                acc[i][j] = __builtin_amdgcn_mfma_f32_16x16x32_bf16(ah[i], bh[j], acc[i][j], 0, 0, 0);
                acc[i][j] = __builtin_amdgcn_mfma_f32_16x16x32_bf16(ah[i], bl[j], acc[i][j], 0, 0, 0);
                acc[i][j] = __builtin_amdgcn_mfma_f32_16x16x32_bf16(al[i], bh[j], acc[i][j], 0, 0, 0);
            }
        }
    }
    // C/D layout: col = lane&15, row = (lane>>4)*4 + reg  (validated round 3)
    #pragma unroll
    for (int i = 0; i < 4; i++) {
        #pragma unroll
        for (int r = 0; r < 4; r++) {
            long R = row0 + wm * 64 + i * 16 + lq * 4 + r;
            if (R < NN) {
                int g = batch[R];
                const float* vrow = vnW + g * D;
                #pragma unroll
                for (int j = 0; j < 4; j++) {
                    int Cc = col0 + wn * 64 + j * 16 + lrow;
                    hx[(size_t)R * D + Cc] = acc[i][j][r] + vrow[Cc];
                }
            }
        }
    }
}

// ---------------- self term: acc = relu(hx + conv_bias) / deg ----------------
__global__ void k_self(const float* __restrict__ hx, const float* __restrict__ cb,
                       const float* __restrict__ deg, float* __restrict__ accb) {
    size_t i = ((size_t)blockIdx.x * 256 + threadIdx.x) * 8;
    if (i >= (size_t)NN * D) return;
    size_t n = i >> 9; int c = (int)(i & 511);
    float invd = 1.0f / deg[n];
    float4 h0 = *(const float4*)(hx + i);
    float4 h1 = *(const float4*)(hx + i + 4);
    float4 b0 = *(const float4*)(cb + c);
    float4 b1 = *(const float4*)(cb + c + 4);
    float4 o0, o1;
    o0.x = fmaxf(h0.x + b0.x, 0.0f) * invd; o0.y = fmaxf(h0.y + b0.y, 0.0f) * invd;
    o0.z = fmaxf(h0.z + b0.z, 0.0f) * invd; o0.w = fmaxf(h0.w + b0.w, 0.0f) * invd;
    o1.x = fmaxf(h1.x + b1.x, 0.0f) * invd; o1.y = fmaxf(h1.y + b1.y, 0.0f) * invd;
    o1.z = fmaxf(h1.z + b1.z, 0.0f) * invd; o1.w = fmaxf(h1.w + b1.w, 0.0f) * invd;
    *(float4*)(accb + i) = o0;
    *(float4*)(accb + i + 4) = o1;
}

// ---------------- edge gather/scatter (fp32) ----------------
__global__ void k_edge(const int* __restrict__ row, const int* __restrict__ col,
                       const float* __restrict__ ea, const float* __restrict__ hx,
                       const float* __restrict__ ew, const float* __restrict__ eb,
                       const float* __restrict__ dis, float* __restrict__ accb) {
    const int lane = threadIdx.x & 63;
    const int wid = blockIdx.x * (blockDim.x >> 6) + (threadIdx.x >> 6);
    const int nw = gridDim.x * (blockDim.x >> 6);
    const int c0 = lane * 8;
    float w0[8], w1[8], bb[8];
    *(float4*)&w0[0] = *(const float4*)(ew + c0);
    *(float4*)&w0[4] = *(const float4*)(ew + c0 + 4);
    *(float4*)&w1[0] = *(const float4*)(ew + D + c0);
    *(float4*)&w1[4] = *(const float4*)(ew + D + c0 + 4);
    *(float4*)&bb[0] = *(const float4*)(eb + c0);
    *(float4*)&bb[4] = *(const float4*)(eb + c0 + 4);
    for (int e = wid; e < NE; e += nw) {
        int r = row[e], c = col[e];
        float nrm = dis[r] * dis[c];
        float a0 = ea[2 * e], a1 = ea[2 * e + 1];
        float hf[8];
        *(float4*)&hf[0] = *(const float4*)(hx + (size_t)r * D + c0);
        *(float4*)&hf[4] = *(const float4*)(hx + (size_t)r * D + c0 + 4);
        float* out = accb + (size_t)c * D + c0;
        #pragma unroll
        for (int q = 0; q < 8; q++) {
            float m = fmaxf(hf[q] + fmaf(a0, w0[q], fmaf(a1, w1[q], bb[q])), 0.0f) * nrm;
            atomicAdd(out + q, m);
        }
    }
}

// ---------------- BN stats ----------------
__global__ void k_bnstats(const float* __restrict__ accb, float* __restrict__ sums) {
    int t = threadIdx.x; int c = 2 * t;
    long n0 = (long)blockIdx.x * 256;
    float s0 = 0, s1 = 0, q0 = 0, q1 = 0;
    for (int rI = 0; rI < 256; rI++) {
        long n = n0 + rI; if (n >= NN) break;
        float2 v = *(const float2*)(accb + (size_t)n * D + c);
        s0 += v.x; q0 = fmaf(v.x, v.x, q0);
        s1 += v.y; q1 = fmaf(v.y, v.y, q1);
    }
    atomicAdd(&sums[c], s0); atomicAdd(&sums[c + 1], s1);
    atomicAdd(&sums[D + c], q0); atomicAdd(&sums[D + c + 1], q1);
}
__global__ void k_bnfin(const float* __restrict__ sums, const float* __restrict__ g,
                        const float* __restrict__ b, float* __restrict__ sc,
                        float* __restrict__ sh) {
    int c = threadIdx.x;  // 512
    float mu = sums[c] * (1.0f / NN);
    float var = fmaxf(sums[D + c] * (1.0f / NN) - mu * mu, 0.0f);
    float rstd = rsqrtf(var + EPS);
    float scale = rstd * g[c];
    sc[c] = scale;
    sh[c] = b[c] - mu * scale;
}

// ------- BN apply + relu + pool; write h as hi/lo bf16 pair (internal) ------
__global__ void k_final(const float* __restrict__ accb, const float* __restrict__ sc,
                        const float* __restrict__ sh, const int* __restrict__ batch,
                        u16* __restrict__ hh, u16* __restrict__ hl,
                        float* __restrict__ pool) {
    int t = threadIdx.x; int c = 2 * t;
    long n0 = (long)blockIdx.x * 256;
    float s0 = sc[c], s1 = sc[c + 1], h0 = sh[c], h1 = sh[c + 1];
    float p0 = 0, p1 = 0; int gc = -1;
    for (int rI = 0; rI < 256; rI++) {
        long n = n0 + rI; if (n >= NN) break;
        float2 v = *(const float2*)(accb + (size_t)n * D + c);
        float a = fmaxf(fmaf(v.x, s0, h0), 0.0f);
        float b = fmaxf(fmaf(v.y, s1, h1), 0.0f);
        u16 ah, al, bh, bl;
        split2(a, ah, al); split2(b, bh, bl);
        ((u32*)(hh + (size_t)n * D))[t] = (u32)ah | ((u32)bh << 16);
        ((u32*)(hl + (size_t)n * D))[t] = (u32)al | ((u32)bl << 16);
        int g = batch[n];
        if (g != gc) {
            if (gc >= 0) { atomicAdd(&pool[gc * D + c], p0); atomicAdd(&pool[gc * D + c + 1], p1); }
            gc = g; p0 = 0; p1 = 0;
        }
        p0 += a; p1 += b;
    }
    if (gc >= 0) { atomicAdd(&pool[gc * D + c], p0); atomicAdd(&pool[gc * D + c + 1], p1); }
}

// ---------------- BN apply, write d_out fp32 (last layer) ----------------
__global__ void k_finalout(const float* __restrict__ accb, const float* __restrict__ sc,
                           const float* __restrict__ sh, float* __restrict__ out) {
    int t = threadIdx.x; int c = 2 * t;
    long n0 = (long)blockIdx.x * 256;
    float s0 = sc[c], s1 = sc[c + 1], h0 = sh[c], h1 = sh[c + 1];
    for (int rI = 0; rI < 256; rI++) {
        long n = n0 + rI; if (n >= NN) break;
        float2 v = *(const float2*)(accb + (size_t)n * D + c);
        ((float2*)out)[n * 256 + t] = make_float2(fmaf(v.x, s0, h0), fmaf(v.y, s1, h1));
    }
}

// ---------------- virtual-node MLP (fp32) ----------------
__global__ void k_mlp1(const float* __restrict__ vn, const float* __restrict__ pool,
                       const float* __restrict__ w1, const float* __restrict__ b1,
                       float* __restrict__ u) {
    int g = blockIdx.x >> 2;
    int j = ((blockIdx.x & 3) << 8) | threadIdx.x;
    __shared__ float sv[D];
    int t = threadIdx.x;
    sv[t] = vn[g * D + t] + pool[g * D + t];
    sv[t + 256] = vn[g * D + t + 256] + pool[g * D + t + 256];
    __syncthreads();
    float acc = b1[j];
    for (int k = 0; k < D; k++) acc = fmaf(sv[k], w1[(size_t)k * 2 * D + j], acc);
    u[(size_t)g * 2 * D + j] = acc;
}
__global__ void k_mbn(const float* __restrict__ u, const float* __restrict__ mg,
                      const float* __restrict__ mb, float* __restrict__ z) {
    int j = blockIdx.x * 256 + threadIdx.x;  // 1024 total
    float s = 0, q = 0;
    for (int g = 0; g < G; g++) { float v = u[(size_t)g * 2 * D + j]; s += v; q = fmaf(v, v, q); }
    float mu = s * (1.0f / G);
    float var = fmaxf(q * (1.0f / G) - mu * mu, 0.0f);
    float rstd = rsqrtf(var + EPS);
    float sc = rstd * mg[j];
    float sh = mb[j] - mu * sc;
    for (int g = 0; g < G; g++)
        z[(size_t)g * 2 * D + j] = fmaxf(fmaf(u[(size_t)g * 2 * D + j], sc, sh), 0.0f);
}
__global__ void k_mlp2(const float* __restrict__ z, const float* __restrict__ w2,
                       const float* __restrict__ b2, float* __restrict__ vn) {
    int g = blockIdx.x >> 1;
    int c = ((blockIdx.x & 1) << 8) | threadIdx.x;
    __shared__ float sz[2 * D];
    int t = threadIdx.x;
    #pragma unroll
    for (int i = 0; i < 4; i++) sz[t + i * 256] = z[(size_t)g * 2 * D + t + i * 256];
    __syncthreads();
    float acc = b2[c];
    for (int k = 0; k < 2 * D; k++) acc = fmaf(sz[k], w2[(size_t)k * D + c], acc);
    vn[g * D + c] = acc;
}

extern "C" void kernel_launch(void* const* d_in, const int* in_sizes, int n_in,
                              void* d_out, int out_size, void* d_ws, size_t ws_size,
                              hipStream_t stream) {
    (void)in_sizes; (void)n_in; (void)out_size; (void)ws_size;
    const int*   x     = (const int*)d_in[0];
    const int*   ndep  = (const int*)d_in[1];
    const int*   ei    = (const int*)d_in[2];
    const int*   batch = (const int*)d_in[3];
    const float* ea    = (const float*)d_in[4];
    const float* te    = (const float*)d_in[5];
    const float* ae    = (const float*)d_in[6];
    const float* de    = (const float*)d_in[7];
    const float* vw    = (const float*)d_in[8];
    const float* lw    = (const float*)d_in[9];
    const float* lb    = (const float*)d_in[10];
    const float* cb    = (const float*)d_in[11];
    const float* ew    = (const float*)d_in[12];
    const float* ebp   = (const float*)d_in[13];
    const float* bng   = (const float*)d_in[14];
    const float* bnb   = (const float*)d_in[15];
    const float* mw1   = (const float*)d_in[16];
    const float* mb1   = (const float*)d_in[17];
    const float* mg    = (const float*)d_in[18];
    const float* mbb   = (const float*)d_in[19];
    const float* mw2   = (const float*)d_in[20];
    const float* mb2   = (const float*)d_in[21];

    char* ws = (char*)d_ws;
    size_t off = 0;
    auto alloc = [&](size_t b) { size_t o = off; off += (b + 255) & ~(size_t)255; return o; };
    u16*  hh   = (u16*)(ws + alloc((size_t)NN * D * 2));
    u16*  hl   = (u16*)(ws + alloc((size_t)NN * D * 2));
    float* hx  = (float*)(ws + alloc((size_t)NN * D * 4));
    float* acc = (float*)(ws + alloc((size_t)NN * D * 4));
    u16*  Wth  = (u16*)(ws + alloc((size_t)L * D * D * 2));
    u16*  Wtl  = (u16*)(ws + alloc((size_t)L * D * D * 2));
    float* vnW = (float*)(ws + alloc((size_t)G * D * 4));
    float* vn  = (float*)(ws + alloc((size_t)G * D * 4));
    float* pool= (float*)(ws + alloc((size_t)G * D * 4));
    float* u   = (float*)(ws + alloc((size_t)G * 2 * D * 4));
    float* z   = (float*)(ws + alloc((size_t)G * 2 * D * 4));
    float* deg = (float*)(ws + alloc((size_t)NN * 4));
    float* dis = (float*)(ws + alloc((size_t)NN * 4));
    int* degint= (int*)(ws + alloc((size_t)NN * 4));
    float* bns = (float*)(ws + alloc((size_t)2 * D * 4));
    float* bsc = (float*)(ws + alloc((size_t)D * 4));
    float* bsh = (float*)(ws + alloc((size_t)D * 4));

    const int* row = ei;
    const int* colp = ei + NE;

    k_zero<<<(NN + 255) / 256, 256, 0, stream>>>((float*)degint, NN);
    k_deg_count<<<(NE + 255) / 256, 256, 0, stream>>>(row, degint);
    k_deg_fin<<<(NN + 255) / 256, 256, 0, stream>>>(degint, deg, dis);
    k_encoder<<<NN, 256, 0, stream>>>(x, ndep, te, ae, de, hh, hl);
    k_wsplit<<<dim3(16, 16, L), dim3(32, 8), 0, stream>>>(lw, Wth, Wtl);
    k_vninit<<<G * D / 256, 256, 0, stream>>>(vw, vn);

    for (int l = 0; l < L; l++) {
        k_vnw<<<G, 512, 0, stream>>>(vn, lw + (size_t)l * D * D, lb + (size_t)l * D, vnW);
        k_gemm3<<<dim3((NN + 127) / 128, 4), 256, 0, stream>>>(
            hh, hl, Wth + (size_t)l * D * D, Wtl + (size_t)l * D * D, vnW, batch, hx);
        k_self<<<(int)(((size_t)NN * D / 8 + 255) / 256), 256, 0, stream>>>(
            hx, cb + (size_t)l * D, deg, acc);
        k_edge<<<2048, 256, 0, stream>>>(row, colp, ea, hx, ew + (size_t)l * 2 * D,
                                         ebp + (size_t)l * D, dis, acc);
        k_zero<<<4, 256, 0, stream>>>(bns, 2 * D);
        k_bnstats<<<(NN + 255) / 256, 256, 0, stream>>>(acc, bns);
        k_bnfin<<<1, D, 0, stream>>>(bns, bng + (size_t)l * D, bnb + (size_t)l * D, bsc, bsh);
        if (l < L - 1) {
            k_zero<<<G * D / 256, 256, 0, stream>>>(pool, G * D);
            k_final<<<(NN + 255) / 256, 256, 0, stream>>>(acc, bsc, bsh, batch, hh, hl, pool);
            k_mlp1<<<G * 4, 256, 0, stream>>>(vn, pool, mw1 + (size_t)l * D * 2 * D,
                                              mb1 + (size_t)l * 2 * D, u);
            k_mbn<<<4, 256, 0, stream>>>(u, mg + (size_t)l * 2 * D, mbb + (size_t)l * 2 * D, z);
            k_mlp2<<<G * 2, 256, 0, stream>>>(z, mw2 + (size_t)l * 2 * D * D,
                                              mb2 + (size_t)l * D, vn);
        } else {
            k_finalout<<<(NN + 255) / 256, 256, 0, stream>>>(acc, bsc, bsh, (float*)d_out);
        }
    }
}